// Round 1
// baseline (595.014 us; speedup 1.0000x reference)
//
#include <hip/hip_runtime.h>

#define SCAN_E 1024  // elements scanned per block in scan_a (256 thr x 4)

// ---- CSR build ----------------------------------------------------------

__global__ void hist_kernel(const int* __restrict__ dst, int* __restrict__ deg, int E) {
    int e = blockIdx.x * blockDim.x + threadIdx.x;
    if (e < E) atomicAdd(&deg[dst[e]], 1);
}

// Per-block exclusive scan of deg -> rp (partial, no global offset); block sums -> bsum.
__global__ void scan_a(const int* __restrict__ deg, int* __restrict__ rp,
                       int* __restrict__ bsum, int N) {
    __shared__ int lds[256];
    int t = threadIdx.x;
    int base = blockIdx.x * SCAN_E + t * 4;
    int v0 = (base + 0 < N) ? deg[base + 0] : 0;
    int v1 = (base + 1 < N) ? deg[base + 1] : 0;
    int v2 = (base + 2 < N) ? deg[base + 2] : 0;
    int v3 = (base + 3 < N) ? deg[base + 3] : 0;
    lds[t] = v0 + v1 + v2 + v3;
    __syncthreads();
    for (int off = 1; off < 256; off <<= 1) {
        int add = (t >= off) ? lds[t - off] : 0;
        __syncthreads();
        lds[t] += add;
        __syncthreads();
    }
    if (t == 255) bsum[blockIdx.x] = lds[255];
    int p = (t == 0) ? 0 : lds[t - 1];
    if (base + 0 < N) rp[base + 0] = p;  p += v0;
    if (base + 1 < N) rp[base + 1] = p;  p += v1;
    if (base + 2 < N) rp[base + 2] = p;  p += v2;
    if (base + 3 < N) rp[base + 3] = p;
}

// Exclusive scan of the (<=1024) block sums; single block of 1024 threads.
__global__ void scan_b(const int* __restrict__ bsum, int* __restrict__ boffs, int nB) {
    __shared__ int lds[1024];
    int t = threadIdx.x;
    lds[t] = (t < nB) ? bsum[t] : 0;
    __syncthreads();
    for (int off = 1; off < 1024; off <<= 1) {
        int add = (t >= off) ? lds[t - off] : 0;
        __syncthreads();
        lds[t] += add;
        __syncthreads();
    }
    boffs[t] = (t == 0) ? 0 : lds[t - 1];
}

__global__ void scan_c(int* __restrict__ rp, const int* __restrict__ boffs, int N, int E) {
    int i = blockIdx.x * blockDim.x + threadIdx.x;
    if (i < N)       rp[i] += boffs[i >> 10];
    else if (i == N) rp[N]  = E;
}

__global__ void fill_kernel(const int* __restrict__ src, const int* __restrict__ dst,
                            const int* __restrict__ rp, int* __restrict__ cur,
                            int* __restrict__ col, int E) {
    int e = blockIdx.x * blockDim.x + threadIdx.x;
    if (e < E) {
        int d = dst[e];
        int p = rp[d] + atomicAdd(&cur[d], 1);
        col[p] = src[e];
    }
}

// ---- Fused aggregate + MLP ---------------------------------------------
// Block = 256 threads = 8 nodes x 32 channels. Per node: v = x[n] + sum_{s in N(n)} x[s],
// then MLP (32 -> relu(16) -> 32) through LDS within the node's 32-lane group.

template <bool RELU_OUT>
__global__ void agg_mlp(const float* __restrict__ xin, const int* __restrict__ rp,
                        const int* __restrict__ col,
                        const float* __restrict__ Wa, const float* __restrict__ ba,
                        const float* __restrict__ Wb, const float* __restrict__ bb,
                        float* __restrict__ out, int N) {
    __shared__ float sWa[32 * 16];   // [c][j]
    __shared__ float sWb[16 * 32];   // [j][co]
    __shared__ float sba[16], sbb[32];
    __shared__ float sv[8][32];      // (x+agg) per node slot
    __shared__ float st1[8][16];     // relu hidden per node slot

    int t = threadIdx.x;
    sWa[t] = Wa[t];  sWa[t + 256] = Wa[t + 256];
    sWb[t] = Wb[t];  sWb[t + 256] = Wb[t + 256];
    if (t < 16) sba[t] = ba[t];
    if (t < 32) sbb[t] = bb[t];
    __syncthreads();

    int ln = t >> 5;          // node slot 0..7
    int c  = t & 31;          // channel 0..31
    int n  = blockIdx.x * 8 + ln;
    bool act = (n < N);

    if (act) {
        float v = xin[(size_t)n * 32 + c];           // (1+eps)*x, eps=0
        int ks = rp[n], ke = rp[n + 1];
        for (int k = ks; k < ke; ++k) {
            int s = col[k];                          // wave-broadcast load
            v += xin[(size_t)s * 32 + c];            // 128B coalesced row
        }
        sv[ln][c] = v;
    }
    __syncthreads();

    if (act && c < 16) {
        float tacc = sba[c];
        #pragma unroll
        for (int cc = 0; cc < 32; ++cc) tacc += sv[ln][cc] * sWa[cc * 16 + c];
        st1[ln][c] = fmaxf(tacc, 0.f);
    }
    __syncthreads();

    if (act) {
        float acc = sbb[c];
        #pragma unroll
        for (int j = 0; j < 16; ++j) acc += st1[ln][j] * sWb[j * 32 + c];
        out[(size_t)n * 32 + c] = RELU_OUT ? fmaxf(acc, 0.f) : acc;
    }
}

// ---- Launch -------------------------------------------------------------

extern "C" void kernel_launch(void* const* d_in, const int* in_sizes, int n_in,
                              void* d_out, int out_size, void* d_ws, size_t ws_size,
                              hipStream_t stream) {
    const float* x  = (const float*)d_in[0];
    const int*   ei = (const int*)d_in[1];
    const float* W1 = (const float*)d_in[2];
    const float* b1 = (const float*)d_in[3];
    const float* W2 = (const float*)d_in[4];
    const float* b2 = (const float*)d_in[5];
    const float* W3 = (const float*)d_in[6];
    const float* b3 = (const float*)d_in[7];
    const float* W4 = (const float*)d_in[8];
    const float* b4 = (const float*)d_in[9];

    const int N = in_sizes[0] / 32;
    const int E = in_sizes[1] / 2;
    const int* src = ei;
    const int* dst = ei + E;

    char* ws = (char*)d_ws;
    size_t o = 0;
    auto alloc = [&](size_t bytes) -> char* {
        o = (o + 255) & ~(size_t)255;
        char* r = ws + o;
        o += bytes;
        return r;
    };
    int*   deg   = (int*)  alloc(4 * (size_t)N);
    int*   rp    = (int*)  alloc(4 * (size_t)(N + 1));
    int*   bsum  = (int*)  alloc(4 * 1024);
    int*   boffs = (int*)  alloc(4 * 1024);
    int*   cur   = (int*)  alloc(4 * (size_t)N);
    int*   col   = (int*)  alloc(4 * (size_t)E);
    float* h     = (float*)alloc(4 * (size_t)N * 32);

    hipMemsetAsync(deg, 0, 4 * (size_t)N, stream);
    hipMemsetAsync(cur, 0, 4 * (size_t)N, stream);

    hist_kernel<<<(E + 255) / 256, 256, 0, stream>>>(dst, deg, E);

    int nB = (N + SCAN_E - 1) / SCAN_E;   // 98 for N=100000; scan_b handles <=1024
    scan_a<<<nB, 256, 0, stream>>>(deg, rp, bsum, N);
    scan_b<<<1, 1024, 0, stream>>>(bsum, boffs, nB);
    scan_c<<<(N + 1 + 255) / 256, 256, 0, stream>>>(rp, boffs, N, E);

    fill_kernel<<<(E + 255) / 256, 256, 0, stream>>>(src, dst, rp, cur, col, E);

    agg_mlp<true ><<<(N + 7) / 8, 256, 0, stream>>>(x, rp, col, W1, b1, W2, b2, h, N);
    agg_mlp<false><<<(N + 7) / 8, 256, 0, stream>>>(h, rp, col, W3, b3, W4, b4,
                                                    (float*)d_out, N);
}

// Round 2
// 478.204 us; speedup vs baseline: 1.2443x; 1.2443x over previous
//
#include <hip/hip_runtime.h>

#define SCAN_E 1024  // elements scanned per block in scan_a (256 thr x 4)

// ---- CSR build ----------------------------------------------------------

__global__ void hist_kernel(const int* __restrict__ dst, int* __restrict__ deg, int E) {
    int e = blockIdx.x * blockDim.x + threadIdx.x;
    if (e < E) atomicAdd(&deg[dst[e]], 1);
}

// Per-block exclusive scan of deg -> rp (partial, no global offset); block sums -> bsum.
__global__ void scan_a(const int* __restrict__ deg, int* __restrict__ rp,
                       int* __restrict__ bsum, int N) {
    __shared__ int lds[256];
    int t = threadIdx.x;
    int base = blockIdx.x * SCAN_E + t * 4;
    int v0 = (base + 0 < N) ? deg[base + 0] : 0;
    int v1 = (base + 1 < N) ? deg[base + 1] : 0;
    int v2 = (base + 2 < N) ? deg[base + 2] : 0;
    int v3 = (base + 3 < N) ? deg[base + 3] : 0;
    lds[t] = v0 + v1 + v2 + v3;
    __syncthreads();
    for (int off = 1; off < 256; off <<= 1) {
        int add = (t >= off) ? lds[t - off] : 0;
        __syncthreads();
        lds[t] += add;
        __syncthreads();
    }
    if (t == 255) bsum[blockIdx.x] = lds[255];
    int p = (t == 0) ? 0 : lds[t - 1];
    if (base + 0 < N) rp[base + 0] = p;  p += v0;
    if (base + 1 < N) rp[base + 1] = p;  p += v1;
    if (base + 2 < N) rp[base + 2] = p;  p += v2;
    if (base + 3 < N) rp[base + 3] = p;
}

// Exclusive scan of the (<=1024) block sums; single block of 1024 threads.
__global__ void scan_b(const int* __restrict__ bsum, int* __restrict__ boffs, int nB) {
    __shared__ int lds[1024];
    int t = threadIdx.x;
    lds[t] = (t < nB) ? bsum[t] : 0;
    __syncthreads();
    for (int off = 1; off < 1024; off <<= 1) {
        int add = (t >= off) ? lds[t - off] : 0;
        __syncthreads();
        lds[t] += add;
        __syncthreads();
    }
    boffs[t] = (t == 0) ? 0 : lds[t - 1];
}

__global__ void scan_c(int* __restrict__ rp, const int* __restrict__ boffs, int N, int E) {
    int i = blockIdx.x * blockDim.x + threadIdx.x;
    if (i < N)       rp[i] += boffs[i >> 10];
    else if (i == N) rp[N]  = E;
}

__global__ void fill_kernel(const int* __restrict__ src, const int* __restrict__ dst,
                            const int* __restrict__ rp, int* __restrict__ cur,
                            int* __restrict__ col, int E) {
    int e = blockIdx.x * blockDim.x + threadIdx.x;
    if (e < E) {
        int d = dst[e];
        int p = rp[d] + atomicAdd(&cur[d], 1);
        col[p] = src[e];
    }
}

// ---- Fused aggregate + MLP ---------------------------------------------
// Block = 256 threads = 8 nodes x 32 channels. Per node: v = x[n] + sum_{s in N(n)} x[s],
// then MLP (32 -> relu(16) -> 32) through LDS within the node's 32-lane group.
// Neighbor loop unrolled 8x: 8 independent row-gathers in flight per node to
// hide LLC latency (the R1 bottleneck: 1 dependent gather at a time, VALUBusy 5%).

template <bool RELU_OUT>
__global__ void agg_mlp(const float* __restrict__ xin, const int* __restrict__ rp,
                        const int* __restrict__ col,
                        const float* __restrict__ Wa, const float* __restrict__ ba,
                        const float* __restrict__ Wb, const float* __restrict__ bb,
                        float* __restrict__ out, int N) {
    __shared__ float sWa[32 * 16];   // [c][j]
    __shared__ float sWb[16 * 32];   // [j][co]
    __shared__ float sba[16], sbb[32];
    __shared__ float sv[8][32];      // (x+agg) per node slot
    __shared__ float st1[8][16];     // relu hidden per node slot

    int t = threadIdx.x;
    sWa[t] = Wa[t];  sWa[t + 256] = Wa[t + 256];
    sWb[t] = Wb[t];  sWb[t + 256] = Wb[t + 256];
    if (t < 16) sba[t] = ba[t];
    if (t < 32) sbb[t] = bb[t];

    int ln = t >> 5;          // node slot 0..7
    int c  = t & 31;          // channel 0..31
    int n  = blockIdx.x * 8 + ln;
    bool act = (n < N);

    if (act) {
        float v = xin[(size_t)n * 32 + c];           // (1+eps)*x, eps=0
        int ks = rp[n], ke = rp[n + 1];
        int k = ks;
        // 8-way unrolled gather: batch the col loads, then 8 independent row loads.
        for (; k + 8 <= ke; k += 8) {
            int s0 = col[k + 0], s1 = col[k + 1], s2 = col[k + 2], s3 = col[k + 3];
            int s4 = col[k + 4], s5 = col[k + 5], s6 = col[k + 6], s7 = col[k + 7];
            float a0 = xin[(size_t)s0 * 32 + c];
            float a1 = xin[(size_t)s1 * 32 + c];
            float a2 = xin[(size_t)s2 * 32 + c];
            float a3 = xin[(size_t)s3 * 32 + c];
            float a4 = xin[(size_t)s4 * 32 + c];
            float a5 = xin[(size_t)s5 * 32 + c];
            float a6 = xin[(size_t)s6 * 32 + c];
            float a7 = xin[(size_t)s7 * 32 + c];
            v += ((a0 + a1) + (a2 + a3)) + ((a4 + a5) + (a6 + a7));
        }
        for (; k < ke; ++k) {
            v += xin[(size_t)col[k] * 32 + c];
        }
        sv[ln][c] = v;
    }
    __syncthreads();

    if (act && c < 16) {
        float tacc = sba[c];
        #pragma unroll
        for (int cc = 0; cc < 32; ++cc) tacc += sv[ln][cc] * sWa[cc * 16 + c];
        st1[ln][c] = fmaxf(tacc, 0.f);
    }
    __syncthreads();

    if (act) {
        float acc = sbb[c];
        #pragma unroll
        for (int j = 0; j < 16; ++j) acc += st1[ln][j] * sWb[j * 32 + c];
        out[(size_t)n * 32 + c] = RELU_OUT ? fmaxf(acc, 0.f) : acc;
    }
}

// ---- Launch -------------------------------------------------------------

extern "C" void kernel_launch(void* const* d_in, const int* in_sizes, int n_in,
                              void* d_out, int out_size, void* d_ws, size_t ws_size,
                              hipStream_t stream) {
    const float* x  = (const float*)d_in[0];
    const int*   ei = (const int*)d_in[1];
    const float* W1 = (const float*)d_in[2];
    const float* b1 = (const float*)d_in[3];
    const float* W2 = (const float*)d_in[4];
    const float* b2 = (const float*)d_in[5];
    const float* W3 = (const float*)d_in[6];
    const float* b3 = (const float*)d_in[7];
    const float* W4 = (const float*)d_in[8];
    const float* b4 = (const float*)d_in[9];

    const int N = in_sizes[0] / 32;
    const int E = in_sizes[1] / 2;
    const int* src = ei;
    const int* dst = ei + E;

    char* ws = (char*)d_ws;
    size_t o = 0;
    auto alloc = [&](size_t bytes) -> char* {
        o = (o + 255) & ~(size_t)255;
        char* r = ws + o;
        o += bytes;
        return r;
    };
    int*   deg   = (int*)  alloc(4 * (size_t)N);
    int*   rp    = (int*)  alloc(4 * (size_t)(N + 1));
    int*   bsum  = (int*)  alloc(4 * 1024);
    int*   boffs = (int*)  alloc(4 * 1024);
    int*   cur   = (int*)  alloc(4 * (size_t)N);
    int*   col   = (int*)  alloc(4 * (size_t)E);
    float* h     = (float*)alloc(4 * (size_t)N * 32);

    hipMemsetAsync(deg, 0, 4 * (size_t)N, stream);
    hipMemsetAsync(cur, 0, 4 * (size_t)N, stream);

    hist_kernel<<<(E + 255) / 256, 256, 0, stream>>>(dst, deg, E);

    int nB = (N + SCAN_E - 1) / SCAN_E;   // 98 for N=100000; scan_b handles <=1024
    scan_a<<<nB, 256, 0, stream>>>(deg, rp, bsum, N);
    scan_b<<<1, 1024, 0, stream>>>(bsum, boffs, nB);
    scan_c<<<(N + 1 + 255) / 256, 256, 0, stream>>>(rp, boffs, N, E);

    fill_kernel<<<(E + 255) / 256, 256, 0, stream>>>(src, dst, rp, cur, col, E);

    agg_mlp<true ><<<(N + 7) / 8, 256, 0, stream>>>(x, rp, col, W1, b1, W2, b2, h, N);
    agg_mlp<false><<<(N + 7) / 8, 256, 0, stream>>>(h, rp, col, W3, b3, W4, b4,
                                                    (float*)d_out, N);
}